// Round 1
// baseline (626.401 us; speedup 1.0000x reference)
//
#include <hip/hip_runtime.h>
#include <hip/hip_bf16.h>

#define BS 4
#define L 2048
#define H 12
#define HD 64
#define R 16
#define HID 768

// M = BS*L = 8192, N = 768, K = 768 for both GEMMs.

// ---------------------------------------------------------------------------
// GEMM -> relu -> per-head dot with ReadingHead -> mask (> 0.5)
// grid (M/64, H) ; block 256. N-tile of 64 == exactly one head.
// ---------------------------------------------------------------------------
__global__ __launch_bounds__(256) void gemm_dot_mask(
    const float* __restrict__ A,      // (8192, 768) hidden
    const float* __restrict__ W,      // (768, 768) K1_w
    const float* __restrict__ bias,   // (768,) K1_b
    const float* __restrict__ RH,     // (H, HD) ReadingHead
    int* __restrict__ mask)           // (BS, H, L)
{
    __shared__ float As[16][64];      // [k][m]
    __shared__ float Bsh[16][64];     // [k][n]
    __shared__ float red[64][17];

    const int mb = blockIdx.x;        // row block
    const int h  = blockIdx.y;        // head == N-tile
    const int tid = threadIdx.x;
    const int ty = tid >> 4, tx = tid & 15;
    const int m0 = mb * 64, n0 = h * 64;

    const int a_k = tid & 15, a_m = tid >> 4;   // A loads: 16 k x 16 m (x4)
    const int b_n = tid & 63, b_k = tid >> 6;   // B loads: 4 k (x4) x 64 n

    float acc[4][4] = {};

    for (int k0 = 0; k0 < HID; k0 += 16) {
#pragma unroll
        for (int i = 0; i < 4; i++) {
            int m = a_m + i * 16;
            As[a_k][m] = A[(size_t)(m0 + m) * HID + k0 + a_k];
        }
#pragma unroll
        for (int i = 0; i < 4; i++) {
            int k = b_k + i * 4;
            Bsh[k][b_n] = W[(size_t)(k0 + k) * HID + n0 + b_n];
        }
        __syncthreads();
#pragma unroll
        for (int kk = 0; kk < 16; kk++) {
            float a[4], b[4];
#pragma unroll
            for (int i = 0; i < 4; i++) a[i] = As[kk][ty * 4 + i];
#pragma unroll
            for (int j = 0; j < 4; j++) b[j] = Bsh[kk][tx * 4 + j];
#pragma unroll
            for (int i = 0; i < 4; i++)
#pragma unroll
                for (int j = 0; j < 4; j++) acc[i][j] = fmaf(a[i], b[j], acc[i][j]);
        }
        __syncthreads();
    }

    // epilogue: relu, multiply by ReadingHead, partial-reduce over the 4 cols
#pragma unroll
    for (int i = 0; i < 4; i++) {
        float p = 0.f;
#pragma unroll
        for (int j = 0; j < 4; j++) {
            int dl = tx * 4 + j;                       // local col = d
            float v = acc[i][j] + bias[n0 + dl];
            v = fmaxf(v, 0.f);
            p = fmaf(v, RH[h * HD + dl], p);
        }
        red[ty * 4 + i][tx] = p;
    }
    __syncthreads();
    if (tid < 64) {
        float s = 0.f;
#pragma unroll
        for (int t = 0; t < 16; t++) s += red[tid][t];
        int row = m0 + tid;            // global (b*L + l)
        int b = row >> 11;             // / L
        int l = row & (L - 1);
        mask[((size_t)b * H + h) * L + l] = (s > 0.5f) ? 1 : 0;
    }
}

// ---------------------------------------------------------------------------
// GEMM -> relu -> V1 (materialized, row-major (BS*L, 768))
// ---------------------------------------------------------------------------
__global__ __launch_bounds__(256) void gemm_v1(
    const float* __restrict__ A,
    const float* __restrict__ W,
    const float* __restrict__ bias,
    float* __restrict__ C)
{
    __shared__ float As[16][64];
    __shared__ float Bsh[16][64];

    const int mb = blockIdx.x, nb = blockIdx.y;
    const int tid = threadIdx.x;
    const int ty = tid >> 4, tx = tid & 15;
    const int m0 = mb * 64, n0 = nb * 64;

    const int a_k = tid & 15, a_m = tid >> 4;
    const int b_n = tid & 63, b_k = tid >> 6;

    float acc[4][4] = {};

    for (int k0 = 0; k0 < HID; k0 += 16) {
#pragma unroll
        for (int i = 0; i < 4; i++) {
            int m = a_m + i * 16;
            As[a_k][m] = A[(size_t)(m0 + m) * HID + k0 + a_k];
        }
#pragma unroll
        for (int i = 0; i < 4; i++) {
            int k = b_k + i * 4;
            Bsh[k][b_n] = W[(size_t)(k0 + k) * HID + n0 + b_n];
        }
        __syncthreads();
#pragma unroll
        for (int kk = 0; kk < 16; kk++) {
            float a[4], b[4];
#pragma unroll
            for (int i = 0; i < 4; i++) a[i] = As[kk][ty * 4 + i];
#pragma unroll
            for (int j = 0; j < 4; j++) b[j] = Bsh[kk][tx * 4 + j];
#pragma unroll
            for (int i = 0; i < 4; i++)
#pragma unroll
                for (int j = 0; j < 4; j++) acc[i][j] = fmaf(a[i], b[j], acc[i][j]);
        }
        __syncthreads();
    }

#pragma unroll
    for (int i = 0; i < 4; i++) {
#pragma unroll
        for (int j = 0; j < 4; j++) {
            int n = n0 + tx * 4 + j;
            float v = acc[i][j] + bias[n];
            C[(size_t)(m0 + ty * 4 + i) * HID + n] = fmaxf(v, 0.f);
        }
    }
}

// ---------------------------------------------------------------------------
// Sequential last-R-valid scan. One wave per (b, h, direction).
// Lane r holds ring slot r. Matches reference semantics exactly:
//   indices 1..L-1 only; output at l is AFTER processing l; l=0 -> zeros.
// fm/bm layout: ((b*L + l)*H + h)*R + r
// ---------------------------------------------------------------------------
__global__ __launch_bounds__(64) void scan_kernel(
    const int* __restrict__ mask,     // (BS, H, L)
    int* __restrict__ fm,
    int* __restrict__ bm)
{
    __shared__ int mrow[L];
    const int bid = blockIdx.x;       // 0..2*BS*H-1
    const bool rev = bid >= BS * H;
    const int bh = rev ? bid - BS * H : bid;
    const int b = bh / H, h = bh % H;
    const int lane = threadIdx.x;

    const int* mp = mask + (size_t)bh * L;
    for (int i = lane; i < L; i += 64) mrow[i] = mp[i];
    __syncthreads();

    int* out = rev ? bm : fm;
    int val = 0;

    if (lane < R) out[((size_t)(b * L + 0) * H + h) * R + lane] = 0;

    if (!rev) {
        for (int l = 1; l < L; l++) {
            int m = mrow[l];
            int up = __shfl_up(val, 1, 64);
            if (m) val = (lane == 0) ? l : up;
            if (lane < R) out[((size_t)(b * L + l) * H + h) * R + lane] = val;
        }
    } else {
        for (int l = L - 1; l >= 1; l--) {
            int m = mrow[l];
            int up = __shfl_up(val, 1, 64);
            if (m) val = (lane == 0) ? l : up;
            if (lane < R) out[((size_t)(b * L + l) * H + h) * R + lane] = val;
        }
    }
}

// ---------------------------------------------------------------------------
// Gather + weighted sum. One block per (b, l); thread = (h-quarter, d).
// ---------------------------------------------------------------------------
__global__ __launch_bounds__(256) void gather_kernel(
    const float* __restrict__ V1,     // (BS*L, 768)
    const int* __restrict__ fm,
    const int* __restrict__ bm,
    const float* __restrict__ bw,     // (H, 2R) flat
    float* __restrict__ out)          // (BS*L, 768)
{
    __shared__ int   sfm[H][R];
    __shared__ int   sbm[H][R];
    __shared__ float swf[H][R];
    __shared__ float swb[H][R];

    const int bl = blockIdx.x;        // b*L + l
    const int b = bl >> 11;
    const int tid = threadIdx.x;

    if (tid < H * R) {
        int h = tid / R, r = tid % R;
        sfm[h][r] = fm[((size_t)bl * H + h) * R + r];
        sbm[h][r] = bm[((size_t)bl * H + h) * R + r];
        swf[h][r] = bw[h * (2 * R) + r];
        swb[h][r] = bw[h * (2 * R) + R + r];
    }
    __syncthreads();

    const int d = tid & 63, hq = tid >> 6;   // hq in 0..3
    const float* Vb = V1 + (size_t)b * L * (H * HD);

#pragma unroll
    for (int hh = 0; hh < 3; hh++) {
        int h = hh * 4 + hq;
        float acc = 0.f;
#pragma unroll
        for (int r = 0; r < R; r++) {
            acc = fmaf(swf[h][r], Vb[(size_t)sfm[h][r] * (H * HD) + h * HD + d], acc);
            acc = fmaf(swb[h][r], Vb[(size_t)sbm[h][r] * (H * HD) + h * HD + d], acc);
        }
        out[(size_t)bl * (H * HD) + h * HD + d] = acc;
    }
}

extern "C" void kernel_launch(void* const* d_in, const int* in_sizes, int n_in,
                              void* d_out, int out_size, void* d_ws, size_t ws_size,
                              hipStream_t stream) {
    const float* hs  = (const float*)d_in[0];   // (BS, L, HID)
    const float* K1w = (const float*)d_in[1];   // (HID, H*HD)
    const float* K1b = (const float*)d_in[2];
    const float* V1w = (const float*)d_in[3];
    const float* V1b = (const float*)d_in[4];
    const float* RH  = (const float*)d_in[5];   // (H, HD)
    const float* bw  = (const float*)d_in[6];   // (1,1,H,1,2R)
    float* out = (float*)d_out;

    // workspace layout
    float* V1  = (float*)d_ws;                           // BS*L*H*HD
    int*   msk = (int*)(V1 + (size_t)BS * L * H * HD);   // BS*H*L
    int*   fm  = msk + (size_t)BS * H * L;               // BS*L*H*R
    int*   bm  = fm + (size_t)BS * L * H * R;            // BS*L*H*R

    dim3 g1(BS * L / 64, H);
    gemm_dot_mask<<<g1, 256, 0, stream>>>(hs, K1w, K1b, RH, msk);
    gemm_v1<<<g1, 256, 0, stream>>>(hs, V1w, V1b, V1);
    scan_kernel<<<2 * BS * H, 64, 0, stream>>>(msk, fm, bm);
    gather_kernel<<<BS * L, 256, 0, stream>>>(V1, fm, bm, bw, out);
}

// Round 2
// 430.005 us; speedup vs baseline: 1.4567x; 1.4567x over previous
//
#include <hip/hip_runtime.h>
#include <hip/hip_bf16.h>

#define BS 4
#define L 2048
#define H 12
#define HD 64
#define R 16
#define HID 768
// M = BS*L = 8192, N = 768, K = 768

typedef __attribute__((ext_vector_type(8))) short s8v;   // 8 bf16 (4 VGPRs)
typedef __attribute__((ext_vector_type(4))) float f32x4;

static __device__ __forceinline__ unsigned short f2bf_bits(float f) {
    __hip_bfloat16 h = __float2bfloat16(f);
    return *reinterpret_cast<unsigned short*>(&h);
}

// ---------------------------------------------------------------------------
// fp32 -> bf16 elementwise (hidden_states), float4 in / ushort4 out
// ---------------------------------------------------------------------------
__global__ __launch_bounds__(256) void convert_hs(
    const float* __restrict__ in, __hip_bfloat16* __restrict__ out)
{
    int i = (blockIdx.x * 256 + threadIdx.x) * 4;
    float4 v = *(const float4*)&in[i];
    ushort4 o;
    o.x = f2bf_bits(v.x); o.y = f2bf_bits(v.y);
    o.z = f2bf_bits(v.z); o.w = f2bf_bits(v.w);
    *(ushort4*)&out[i] = o;
}

// ---------------------------------------------------------------------------
// V1_w (k,n) fp32 -> Wt (n,k) bf16, 32x32 LDS tile transpose
// ---------------------------------------------------------------------------
__global__ __launch_bounds__(256) void transpose_wt(
    const float* __restrict__ in, __hip_bfloat16* __restrict__ out)
{
    __shared__ float s[32][33];
    const int c = threadIdx.x & 31, r8 = threadIdx.x >> 5;  // r8 in 0..7
    const int kt = blockIdx.x * 32, nt = blockIdx.y * 32;
#pragma unroll
    for (int rr = 0; rr < 4; ++rr) {
        int k = r8 + rr * 8;
        s[k][c] = in[(size_t)(kt + k) * HID + nt + c];
    }
    __syncthreads();
#pragma unroll
    for (int rr = 0; rr < 4; ++rr) {
        int n = r8 + rr * 8;
        out[(size_t)(nt + n) * HID + kt + c] = __float2bfloat16(s[c][n]);
    }
}

// ---------------------------------------------------------------------------
// Mask GEMM (fp32 vector, must stay fp32: hard threshold at 0.5).
// Tile 128(M) x 64(N=one head). Conflict-free staging, float4 LDS reads.
// Fused epilogue: relu -> dot(ReadingHead) -> in-wave shfl reduce -> mask.
// ---------------------------------------------------------------------------
__global__ __launch_bounds__(256) void gemm_dot_mask(
    const float* __restrict__ A,      // (8192, 768)
    const float* __restrict__ W,      // (768, 768)
    const float* __restrict__ bias,
    const float* __restrict__ RH,     // (H, HD)
    int* __restrict__ mask)           // (BS*H, L)
{
    __shared__ float As[16][128];     // [k][m]
    __shared__ float Bs[16][64];      // [k][n]

    const int tid = threadIdx.x;
    const int m0 = blockIdx.x * 128;
    const int h  = blockIdx.y;
    const int n0 = h * 64;
    const int ty = tid >> 4, tx = tid & 15;

    float acc[8][4] = {};

    for (int k0 = 0; k0 < HID; k0 += 16) {
        // A stage: thread loads float4 along k, scatters 4 scalar writes.
        // Write bank = m%32; wave lanes have consecutive m -> 2-way max (free).
#pragma unroll
        for (int it = 0; it < 2; ++it) {
            int slot = tid + it * 256;          // 0..511
            int m = slot & 127, kq = slot >> 7; // kq 0..3
            float4 v = *(const float4*)&A[(size_t)(m0 + m) * HID + k0 + kq * 4];
            As[kq * 4 + 0][m] = v.x;
            As[kq * 4 + 1][m] = v.y;
            As[kq * 4 + 2][m] = v.z;
            As[kq * 4 + 3][m] = v.w;
        }
        {
            int k = tid >> 4, n4 = tid & 15;
            *(float4*)&Bs[k][n4 * 4] =
                *(const float4*)&W[(size_t)(k0 + k) * HID + n0 + n4 * 4];
        }
        __syncthreads();
#pragma unroll
        for (int kk = 0; kk < 16; ++kk) {
            float4 a0 = *(const float4*)&As[kk][ty * 8];
            float4 a1 = *(const float4*)&As[kk][ty * 8 + 4];
            float4 b  = *(const float4*)&Bs[kk][tx * 4];
            float a[8] = {a0.x, a0.y, a0.z, a0.w, a1.x, a1.y, a1.z, a1.w};
            float bb[4] = {b.x, b.y, b.z, b.w};
#pragma unroll
            for (int i = 0; i < 8; ++i)
#pragma unroll
                for (int j = 0; j < 4; ++j)
                    acc[i][j] = fmaf(a[i], bb[j], acc[i][j]);
        }
        __syncthreads();
    }

    const float4 b4  = *(const float4*)&bias[n0 + tx * 4];
    const float4 rh4 = *(const float4*)&RH[h * HD + tx * 4];
#pragma unroll
    for (int i = 0; i < 8; ++i) {
        float p = 0.f;
        p = fmaf(fmaxf(acc[i][0] + b4.x, 0.f), rh4.x, p);
        p = fmaf(fmaxf(acc[i][1] + b4.y, 0.f), rh4.y, p);
        p = fmaf(fmaxf(acc[i][2] + b4.z, 0.f), rh4.z, p);
        p = fmaf(fmaxf(acc[i][3] + b4.w, 0.f), rh4.w, p);
#pragma unroll
        for (int s = 1; s < 16; s <<= 1) p += __shfl_xor(p, s, 64);
        if (tx == 0) {
            int row = m0 + ty * 8 + i;       // b*L + l
            int b = row >> 11, l = row & (L - 1);
            mask[((b * H + h) << 11) + l] = (p > 0.5f) ? 1 : 0;
        }
    }
}

// ---------------------------------------------------------------------------
// V1 GEMM: bf16 MFMA 16x16x32, 128x128 block tile, 4 waves of 64x64.
// A (m,k) bf16 row-major; Bt (n,k) bf16 row-major. LDS rows padded 32->40
// (conflict-free b128 frag reads). Epilogue: +bias, relu, store bf16.
// ---------------------------------------------------------------------------
__global__ __launch_bounds__(256) void gemm_v1_mfma(
    const __hip_bfloat16* __restrict__ A,    // (8192, 768)
    const __hip_bfloat16* __restrict__ Bt,   // (768, 768) = W^T
    const float* __restrict__ bias,
    __hip_bfloat16* __restrict__ C)          // (8192, 768) relu'd
{
    __shared__ __hip_bfloat16 As[128][40];
    __shared__ __hip_bfloat16 Bs[128][40];

    const int tid = threadIdx.x;
    const int m0 = blockIdx.x * 128, n0 = blockIdx.y * 128;
    const int wid = tid >> 6, lane = tid & 63;
    const int quad = lane >> 4, lm = lane & 15;
    const int wm = wid & 1, wn = wid >> 1;

    f32x4 acc[4][4] = {};

    for (int k0 = 0; k0 < HID; k0 += 32) {
#pragma unroll
        for (int it = 0; it < 2; ++it) {
            int slot = tid + it * 256;            // 0..511
            int r = slot & 127, kq = slot >> 7;   // kq 0..3, 8 bf16 each
            *(float4*)&As[r][kq * 8] =
                *(const float4*)&A[(size_t)(m0 + r) * HID + k0 + kq * 8];
            *(float4*)&Bs[r][kq * 8] =
                *(const float4*)&Bt[(size_t)(n0 + r) * HID + k0 + kq * 8];
        }
        __syncthreads();
        s8v af[4], bf[4];
#pragma unroll
        for (int i = 0; i < 4; ++i)
            af[i] = *(const s8v*)&As[wm * 64 + i * 16 + lm][quad * 8];
#pragma unroll
        for (int j = 0; j < 4; ++j)
            bf[j] = *(const s8v*)&Bs[wn * 64 + j * 16 + lm][quad * 8];
#pragma unroll
        for (int i = 0; i < 4; ++i)
#pragma unroll
            for (int j = 0; j < 4; ++j)
                acc[i][j] = __builtin_amdgcn_mfma_f32_16x16x32_bf16(
                    af[i], bf[j], acc[i][j], 0, 0, 0);
        __syncthreads();
    }

    // C/D layout: col = lane&15, row = quad*4 + reg  [m89/m91 verified]
#pragma unroll
    for (int i = 0; i < 4; ++i) {
        int row_b = m0 + wm * 64 + i * 16 + quad * 4;
#pragma unroll
        for (int j = 0; j < 4; ++j) {
            int col = n0 + wn * 64 + j * 16 + lm;
            float bsv = bias[col];
#pragma unroll
            for (int reg = 0; reg < 4; ++reg) {
                float v = acc[i][j][reg] + bsv;
                C[(size_t)(row_b + reg) * HID + col] =
                    __float2bfloat16(fmaxf(v, 0.f));
            }
        }
    }
}

// ---------------------------------------------------------------------------
// Sequential last-R-valid scan. One wave per (b, h, direction).
// ---------------------------------------------------------------------------
__global__ __launch_bounds__(64) void scan_kernel(
    const int* __restrict__ mask,     // (BS*H, L)
    short* __restrict__ fm,
    short* __restrict__ bm)
{
    __shared__ int mrow[L];
    const int bid = blockIdx.x;
    const bool rev = bid >= BS * H;
    const int bh = rev ? bid - BS * H : bid;
    const int b = bh / H, h = bh % H;
    const int lane = threadIdx.x;

    const int* mp = mask + (size_t)bh * L;
    for (int i = lane; i < L; i += 64) mrow[i] = mp[i];
    __syncthreads();

    short* out = rev ? bm : fm;
    int val = 0;
    if (lane < R) out[((size_t)(b * L) * H + h) * R + lane] = 0;

    if (!rev) {
        for (int l = 1; l < L; l++) {
            int m = mrow[l];
            int up = __shfl_up(val, 1, 64);
            if (m) val = (lane == 0) ? l : up;
            if (lane < R) out[((size_t)(b * L + l) * H + h) * R + lane] = (short)val;
        }
    } else {
        for (int l = L - 1; l >= 1; l--) {
            int m = mrow[l];
            int up = __shfl_up(val, 1, 64);
            if (m) val = (lane == 0) ? l : up;
            if (lane < R) out[((size_t)(b * L + l) * H + h) * R + lane] = (short)val;
        }
    }
}

// ---------------------------------------------------------------------------
// Gather + weighted sum. Block per (b,l). Wave w -> heads 3w..3w+2.
// Lane: d4 = lane&15 (float4 of d), g = lane>>4 (4 gather rows in flight).
// V1 is bf16 (8B loads); shfl-reduce over g; float4 stores.
// ---------------------------------------------------------------------------
__global__ __launch_bounds__(256) void gather_kernel(
    const __hip_bfloat16* __restrict__ V1,   // (8192, 768) bf16
    const short* __restrict__ fm,
    const short* __restrict__ bm,
    const float* __restrict__ bw,            // (H, 2R)
    float* __restrict__ out)                 // (8192, 768) fp32
{
    __shared__ short sidx[2][H][R];
    __shared__ float sw[2][H][R];

    const int bl = blockIdx.x;               // b*L + l
    const int b = bl >> 11;
    const int tid = threadIdx.x;

    if (tid < H * R) {
        int h = tid >> 4, r = tid & 15;
        sidx[0][h][r] = fm[((size_t)bl * H + h) * R + r];
        sidx[1][h][r] = bm[((size_t)bl * H + h) * R + r];
        sw[0][h][r] = bw[h * (2 * R) + r];
        sw[1][h][r] = bw[h * (2 * R) + R + r];
    }
    __syncthreads();

    const int wid = tid >> 6, lane = tid & 63;
    const int d4 = lane & 15, g = lane >> 4;
    const __hip_bfloat16* Vb = V1 + (size_t)b * L * HID;

#pragma unroll
    for (int hh = 0; hh < 3; ++hh) {
        int h = wid * 3 + hh;
        float a0 = 0.f, a1 = 0.f, a2 = 0.f, a3 = 0.f;
#pragma unroll
        for (int it = 0; it < 8; ++it) {
            int slot = g + it * 4;           // 0..31
            int dir = slot >> 4, r = slot & 15;
            int idx = sidx[dir][h][r];
            float w = sw[dir][h][r];
            const __hip_bfloat16* p = Vb + (size_t)idx * HID + h * HD + d4 * 4;
            uint2 uv = *(const uint2*)p;
            a0 = fmaf(w, __uint_as_float(uv.x << 16), a0);
            a1 = fmaf(w, __uint_as_float(uv.x & 0xffff0000u), a1);
            a2 = fmaf(w, __uint_as_float(uv.y << 16), a2);
            a3 = fmaf(w, __uint_as_float(uv.y & 0xffff0000u), a3);
        }
        a0 += __shfl_xor(a0, 16, 64); a0 += __shfl_xor(a0, 32, 64);
        a1 += __shfl_xor(a1, 16, 64); a1 += __shfl_xor(a1, 32, 64);
        a2 += __shfl_xor(a2, 16, 64); a2 += __shfl_xor(a2, 32, 64);
        a3 += __shfl_xor(a3, 16, 64); a3 += __shfl_xor(a3, 32, 64);
        if (g == 0) {
            float4 o; o.x = a0; o.y = a1; o.z = a2; o.w = a3;
            *(float4*)&out[(size_t)bl * HID + h * HD + d4 * 4] = o;
        }
    }
}

extern "C" void kernel_launch(void* const* d_in, const int* in_sizes, int n_in,
                              void* d_out, int out_size, void* d_ws, size_t ws_size,
                              hipStream_t stream) {
    const float* hs  = (const float*)d_in[0];
    const float* K1w = (const float*)d_in[1];
    const float* K1b = (const float*)d_in[2];
    const float* V1w = (const float*)d_in[3];
    const float* V1b = (const float*)d_in[4];
    const float* RH  = (const float*)d_in[5];
    const float* bw  = (const float*)d_in[6];
    float* out = (float*)d_out;

    // workspace layout (fm/bm alias Abf: Abf dead after gemm_v1_mfma,
    // scan launches after it on the same stream -> safe)
    char* ws = (char*)d_ws;
    __hip_bfloat16* Abf = (__hip_bfloat16*)ws;                       // 12,582,912 B
    __hip_bfloat16* Wt  = (__hip_bfloat16*)(ws + 12582912);          //  1,179,648 B
    __hip_bfloat16* V1  = (__hip_bfloat16*)(ws + 13762560);          // 12,582,912 B
    int*   msk = (int*)(ws + 26345472);                              //    393,216 B
    short* fm  = (short*)ws;                                         // alias Abf
    short* bm  = fm + (size_t)BS * L * H * R;                        // 3,145,728 B each

    gemm_dot_mask<<<dim3(BS * L / 128, H), 256, 0, stream>>>(hs, K1w, K1b, RH, msk);
    convert_hs<<<(BS * L * HID) / (256 * 4), 256, 0, stream>>>(hs, Abf);
    transpose_wt<<<dim3(HID / 32, HID / 32), 256, 0, stream>>>(V1w, Wt);
    gemm_v1_mfma<<<dim3(BS * L / 128, HID / 128), 256, 0, stream>>>(Abf, Wt, V1b, V1);
    scan_kernel<<<2 * BS * H, 64, 0, stream>>>(msk, fm, bm);
    gather_kernel<<<BS * L, 256, 0, stream>>>(V1, fm, bm, bw, out);
}

// Round 3
// 280.307 us; speedup vs baseline: 2.2347x; 1.5341x over previous
//
#include <hip/hip_runtime.h>
#include <hip/hip_bf16.h>

#define BS 4
#define L 2048
#define H 12
#define HD 64
#define R 16
#define HID 768
// M = BS*L = 8192, N = 768, K = 768

typedef __attribute__((ext_vector_type(8))) short s8v;   // 8 bf16 (4 VGPRs)
typedef __attribute__((ext_vector_type(4))) float f32x4;

static __device__ __forceinline__ unsigned short f2bf_bits(float f) {
    __hip_bfloat16 h = __float2bfloat16(f);
    return *reinterpret_cast<unsigned short*>(&h);
}

// ---------------------------------------------------------------------------
// fp32 -> bf16 elementwise (hidden_states), float4 in / ushort4 out
// ---------------------------------------------------------------------------
__global__ __launch_bounds__(256) void convert_hs(
    const float* __restrict__ in, __hip_bfloat16* __restrict__ out)
{
    int i = (blockIdx.x * 256 + threadIdx.x) * 4;
    float4 v = *(const float4*)&in[i];
    ushort4 o;
    o.x = f2bf_bits(v.x); o.y = f2bf_bits(v.y);
    o.z = f2bf_bits(v.z); o.w = f2bf_bits(v.w);
    *(ushort4*)&out[i] = o;
}

// ---------------------------------------------------------------------------
// V1_w (k,n) fp32 -> Wt (n,k) bf16, 32x32 LDS tile transpose
// ---------------------------------------------------------------------------
__global__ __launch_bounds__(256) void transpose_wt(
    const float* __restrict__ in, __hip_bfloat16* __restrict__ out)
{
    __shared__ float s[32][33];
    const int c = threadIdx.x & 31, r8 = threadIdx.x >> 5;  // r8 in 0..7
    const int kt = blockIdx.x * 32, nt = blockIdx.y * 32;
#pragma unroll
    for (int rr = 0; rr < 4; ++rr) {
        int k = r8 + rr * 8;
        s[k][c] = in[(size_t)(kt + k) * HID + nt + c];
    }
    __syncthreads();
#pragma unroll
    for (int rr = 0; rr < 4; ++rr) {
        int n = r8 + rr * 8;
        out[(size_t)(nt + n) * HID + kt + c] = __float2bfloat16(s[c][n]);
    }
}

// ---------------------------------------------------------------------------
// Mask GEMM (fp32 vector, must stay fp32: hard threshold at 0.5).
// Tile 128(M) x 64(N=one head). Conflict-free staging, float4 LDS reads.
// Fused epilogue: relu -> dot(ReadingHead) -> in-wave shfl reduce -> mask.
// ---------------------------------------------------------------------------
__global__ __launch_bounds__(256) void gemm_dot_mask(
    const float* __restrict__ A,      // (8192, 768)
    const float* __restrict__ W,      // (768, 768)
    const float* __restrict__ bias,
    const float* __restrict__ RH,     // (H, HD)
    int* __restrict__ mask)           // (BS*H, L)
{
    __shared__ float As[16][128];     // [k][m]
    __shared__ float Bs[16][64];      // [k][n]

    const int tid = threadIdx.x;
    const int m0 = blockIdx.x * 128;
    const int h  = blockIdx.y;
    const int n0 = h * 64;
    const int ty = tid >> 4, tx = tid & 15;

    float acc[8][4] = {};

    for (int k0 = 0; k0 < HID; k0 += 16) {
#pragma unroll
        for (int it = 0; it < 2; ++it) {
            int slot = tid + it * 256;          // 0..511
            int m = slot & 127, kq = slot >> 7; // kq 0..3
            float4 v = *(const float4*)&A[(size_t)(m0 + m) * HID + k0 + kq * 4];
            As[kq * 4 + 0][m] = v.x;
            As[kq * 4 + 1][m] = v.y;
            As[kq * 4 + 2][m] = v.z;
            As[kq * 4 + 3][m] = v.w;
        }
        {
            int k = tid >> 4, n4 = tid & 15;
            *(float4*)&Bs[k][n4 * 4] =
                *(const float4*)&W[(size_t)(k0 + k) * HID + n0 + n4 * 4];
        }
        __syncthreads();
#pragma unroll
        for (int kk = 0; kk < 16; ++kk) {
            float4 a0 = *(const float4*)&As[kk][ty * 8];
            float4 a1 = *(const float4*)&As[kk][ty * 8 + 4];
            float4 b  = *(const float4*)&Bs[kk][tx * 4];
            float a[8] = {a0.x, a0.y, a0.z, a0.w, a1.x, a1.y, a1.z, a1.w};
            float bb[4] = {b.x, b.y, b.z, b.w};
#pragma unroll
            for (int i = 0; i < 8; ++i)
#pragma unroll
                for (int j = 0; j < 4; ++j)
                    acc[i][j] = fmaf(a[i], bb[j], acc[i][j]);
        }
        __syncthreads();
    }

    const float4 b4  = *(const float4*)&bias[n0 + tx * 4];
    const float4 rh4 = *(const float4*)&RH[h * HD + tx * 4];
#pragma unroll
    for (int i = 0; i < 8; ++i) {
        float p = 0.f;
        p = fmaf(fmaxf(acc[i][0] + b4.x, 0.f), rh4.x, p);
        p = fmaf(fmaxf(acc[i][1] + b4.y, 0.f), rh4.y, p);
        p = fmaf(fmaxf(acc[i][2] + b4.z, 0.f), rh4.z, p);
        p = fmaf(fmaxf(acc[i][3] + b4.w, 0.f), rh4.w, p);
#pragma unroll
        for (int s = 1; s < 16; s <<= 1) p += __shfl_xor(p, s, 64);
        if (tx == 0) {
            int row = m0 + ty * 8 + i;       // b*L + l
            int b = row >> 11, l = row & (L - 1);
            mask[((b * H + h) << 11) + l] = (p > 0.5f) ? 1 : 0;
        }
    }
}

// ---------------------------------------------------------------------------
// V1 GEMM: bf16 MFMA 16x16x32, 128x128 block tile, 4 waves of 64x64.
// ---------------------------------------------------------------------------
__global__ __launch_bounds__(256) void gemm_v1_mfma(
    const __hip_bfloat16* __restrict__ A,    // (8192, 768)
    const __hip_bfloat16* __restrict__ Bt,   // (768, 768) = W^T
    const float* __restrict__ bias,
    __hip_bfloat16* __restrict__ C)          // (8192, 768) relu'd
{
    __shared__ __hip_bfloat16 As[128][40];
    __shared__ __hip_bfloat16 Bs[128][40];

    const int tid = threadIdx.x;
    const int m0 = blockIdx.x * 128, n0 = blockIdx.y * 128;
    const int wid = tid >> 6, lane = tid & 63;
    const int quad = lane >> 4, lm = lane & 15;
    const int wm = wid & 1, wn = wid >> 1;

    f32x4 acc[4][4] = {};

    for (int k0 = 0; k0 < HID; k0 += 32) {
#pragma unroll
        for (int it = 0; it < 2; ++it) {
            int slot = tid + it * 256;            // 0..511
            int r = slot & 127, kq = slot >> 7;   // kq 0..3, 8 bf16 each
            *(float4*)&As[r][kq * 8] =
                *(const float4*)&A[(size_t)(m0 + r) * HID + k0 + kq * 8];
            *(float4*)&Bs[r][kq * 8] =
                *(const float4*)&Bt[(size_t)(n0 + r) * HID + k0 + kq * 8];
        }
        __syncthreads();
        s8v af[4], bf[4];
#pragma unroll
        for (int i = 0; i < 4; ++i)
            af[i] = *(const s8v*)&As[wm * 64 + i * 16 + lm][quad * 8];
#pragma unroll
        for (int j = 0; j < 4; ++j)
            bf[j] = *(const s8v*)&Bs[wn * 64 + j * 16 + lm][quad * 8];
#pragma unroll
        for (int i = 0; i < 4; ++i)
#pragma unroll
            for (int j = 0; j < 4; ++j)
                acc[i][j] = __builtin_amdgcn_mfma_f32_16x16x32_bf16(
                    af[i], bf[j], acc[i][j], 0, 0, 0);
        __syncthreads();
    }

    // C/D layout: col = lane&15, row = quad*4 + reg  [m89/m91 verified]
#pragma unroll
    for (int i = 0; i < 4; ++i) {
        int row_b = m0 + wm * 64 + i * 16 + quad * 4;
#pragma unroll
        for (int j = 0; j < 4; ++j) {
            int col = n0 + wn * 64 + j * 16 + lm;
            float bsv = bias[col];
#pragma unroll
            for (int reg = 0; reg < 4; ++reg) {
                float v = acc[i][j][reg] + bsv;
                C[(size_t)(row_b + reg) * HID + col] =
                    __float2bfloat16(fmaxf(v, 0.f));
            }
        }
    }
}

// ---------------------------------------------------------------------------
// Parallel rank/select scan. One block per (b,h).
//   P[l] = # valid indices in [1..l];  S[j] = j-th valid index (1-based).
//   fm[l][r] = S[P[l]-r]      if P[l]-r   >= 1 else 0
//   bm[l][r] = S[P[l-1]+1+r]  if P[l-1]+1+r <= T else 0  (l=0 -> zeros)
// Matches the sequential last-R-valid semantics exactly.
// ---------------------------------------------------------------------------
__global__ __launch_bounds__(256) void scan_kernel(
    const int* __restrict__ mask,     // (BS*H, L)
    short* __restrict__ fm,
    short* __restrict__ bm)
{
    __shared__ unsigned short P[L];
    __shared__ unsigned short S[L];
    __shared__ int wsum[4];

    const int bh = blockIdx.x;        // b*H + h
    const int b = bh / H, h = bh % H;
    const int tid = threadIdx.x;
    const int base = tid * 8;
    const int lane = tid & 63, w = tid >> 6;

    // local 8-element load + inclusive prefix (index 0 excluded by reference)
    int m[8], c[8];
    int run = 0;
#pragma unroll
    for (int i = 0; i < 8; ++i) {
        int l = base + i;
        m[i] = (l >= 1) ? mask[((size_t)bh << 11) + l] : 0;
        run += m[i];
        c[i] = run;
    }
    // wave inclusive scan of per-thread totals
    int sc = run;
#pragma unroll
    for (int s = 1; s < 64; s <<= 1) {
        int v = __shfl_up(sc, s, 64);
        if (lane >= s) sc += v;
    }
    if (lane == 63) wsum[w] = sc;
    __syncthreads();
    int woff = 0;
    for (int i = 0; i < 4; ++i) if (i < w) woff += wsum[i];
    const int ex = woff + sc - run;   // exclusive prefix for this thread

#pragma unroll
    for (int i = 0; i < 8; ++i) {
        int l = base + i;
        int pc = ex + c[i];
        P[l] = (unsigned short)pc;
        if (m[i]) S[pc] = (unsigned short)l;
    }
    __syncthreads();
    const int T = P[L - 1];

#pragma unroll
    for (int i = 0; i < 8; ++i) {
        int l = base + i;
        int cc = ex + c[i];                       // == P[l]
        union { unsigned short s[16]; uint4 q[2]; } uf, ub;
#pragma unroll
        for (int r = 0; r < 16; ++r)
            uf.s[r] = (cc - r >= 1) ? S[cc - r] : (unsigned short)0;
        int cp = (l >= 1) ? (int)P[l - 1] : 0;
#pragma unroll
        for (int r = 0; r < 16; ++r) {
            int j = cp + 1 + r;
            ub.s[r] = (l >= 1 && j <= T) ? S[j] : (unsigned short)0;
        }
        size_t off = ((size_t)(b * L + l) * H + h) * R;   // 32B aligned
        *(uint4*)&fm[off] = uf.q[0];
        *(uint4*)&fm[off + 8] = uf.q[1];
        *(uint4*)&bm[off] = ub.q[0];
        *(uint4*)&bm[off + 8] = ub.q[1];
    }
}

// ---------------------------------------------------------------------------
// Gather + weighted sum. 192 threads, TWO l-values per block.
// Thread = (l_sub, h, d8): owns 8 bf16 columns, accumulates all 32 (dir,r)
// slots with 16B loads, no shuffle reduce, two float4 stores.
// ---------------------------------------------------------------------------
__global__ __launch_bounds__(192) void gather_kernel(
    const __hip_bfloat16* __restrict__ V1,   // (8192, 768) bf16
    const short* __restrict__ fm,
    const short* __restrict__ bm,
    const float* __restrict__ bw,            // (H, 2R)
    float* __restrict__ out)                 // (8192, 768) fp32
{
    __shared__ short sidx[2][2][H][R];       // [l_sub][dir][h][r]
    __shared__ float sw[2][H][R];            // [dir][h][r]

    const int bl0 = blockIdx.x * 2;          // b*L + l (even); pair shares b
    const int b = bl0 >> 11;
    const int tid = threadIdx.x;

    for (int i = tid; i < 2 * 2 * H * R; i += 192) {
        int ls = i / (2 * H * R), rem = i % (2 * H * R);
        int dir = rem / (H * R), hr = rem % (H * R);
        int h = hr >> 4, r = hr & 15;
        const short* src = dir ? bm : fm;
        sidx[ls][dir][h][r] = src[((size_t)(bl0 + ls) * H + h) * R + r];
    }
    for (int i = tid; i < 2 * H * R; i += 192) {
        int dir = i / (H * R), hr = i % (H * R);
        int h = hr >> 4, r = hr & 15;
        sw[dir][h][r] = bw[h * (2 * R) + dir * R + r];
    }
    __syncthreads();

    const int ls = tid / 96, t = tid % 96;
    const int h = t >> 3, d8 = t & 7;
    const __hip_bfloat16* Vb = V1 + (size_t)b * L * HID;

    float a[8] = {};
#pragma unroll
    for (int slot = 0; slot < 32; ++slot) {
        int dir = slot >> 4, r = slot & 15;
        int idx = sidx[ls][dir][h][r];
        float wv = sw[dir][h][r];
        const __hip_bfloat16* p = Vb + (size_t)idx * HID + h * HD + d8 * 8;
        uint4 uv = *(const uint4*)p;
        a[0] = fmaf(wv, __uint_as_float(uv.x << 16), a[0]);
        a[1] = fmaf(wv, __uint_as_float(uv.x & 0xffff0000u), a[1]);
        a[2] = fmaf(wv, __uint_as_float(uv.y << 16), a[2]);
        a[3] = fmaf(wv, __uint_as_float(uv.y & 0xffff0000u), a[3]);
        a[4] = fmaf(wv, __uint_as_float(uv.z << 16), a[4]);
        a[5] = fmaf(wv, __uint_as_float(uv.z & 0xffff0000u), a[5]);
        a[6] = fmaf(wv, __uint_as_float(uv.w << 16), a[6]);
        a[7] = fmaf(wv, __uint_as_float(uv.w & 0xffff0000u), a[7]);
    }
    float* op = &out[(size_t)(bl0 + ls) * HID + h * HD + d8 * 8];
    float4 o0, o1;
    o0.x = a[0]; o0.y = a[1]; o0.z = a[2]; o0.w = a[3];
    o1.x = a[4]; o1.y = a[5]; o1.z = a[6]; o1.w = a[7];
    *(float4*)op = o0;
    *(float4*)(op + 4) = o1;
}

extern "C" void kernel_launch(void* const* d_in, const int* in_sizes, int n_in,
                              void* d_out, int out_size, void* d_ws, size_t ws_size,
                              hipStream_t stream) {
    const float* hs  = (const float*)d_in[0];
    const float* K1w = (const float*)d_in[1];
    const float* K1b = (const float*)d_in[2];
    const float* V1w = (const float*)d_in[3];
    const float* V1b = (const float*)d_in[4];
    const float* RH  = (const float*)d_in[5];
    const float* bw  = (const float*)d_in[6];
    float* out = (float*)d_out;

    // workspace layout (fm/bm alias Abf: Abf dead after gemm_v1_mfma,
    // scan launches after it on the same stream -> safe)
    char* ws = (char*)d_ws;
    __hip_bfloat16* Abf = (__hip_bfloat16*)ws;                       // 12,582,912 B
    __hip_bfloat16* Wt  = (__hip_bfloat16*)(ws + 12582912);          //  1,179,648 B
    __hip_bfloat16* V1  = (__hip_bfloat16*)(ws + 13762560);          // 12,582,912 B
    int*   msk = (int*)(ws + 26345472);                              //    393,216 B
    short* fm  = (short*)ws;                                         // alias Abf
    short* bm  = fm + (size_t)BS * L * H * R;                        // 3,145,728 B each

    gemm_dot_mask<<<dim3(BS * L / 128, H), 256, 0, stream>>>(hs, K1w, K1b, RH, msk);
    convert_hs<<<(BS * L * HID) / (256 * 4), 256, 0, stream>>>(hs, Abf);
    transpose_wt<<<dim3(HID / 32, HID / 32), 256, 0, stream>>>(V1w, Wt);
    gemm_v1_mfma<<<dim3(BS * L / 128, HID / 128), 256, 0, stream>>>(Abf, Wt, V1b, V1);
    scan_kernel<<<BS * H, 256, 0, stream>>>(msk, fm, bm);
    gather_kernel<<<BS * L / 2, 192, 0, stream>>>(V1, fm, bm, bw, out);
}

// Round 4
// 277.741 us; speedup vs baseline: 2.2553x; 1.0092x over previous
//
#include <hip/hip_runtime.h>
#include <hip/hip_bf16.h>

#define BS 4
#define L 2048
#define H 12
#define HD 64
#define R 16
#define HID 768
#define MARGIN 0.02f
// M = BS*L = 8192, N = 768, K = 768

typedef __attribute__((ext_vector_type(8))) short s8v;   // 8 bf16 (4 VGPRs)
typedef __attribute__((ext_vector_type(4))) float f32x4;

static __device__ __forceinline__ unsigned short f2bf_bits(float f) {
    __hip_bfloat16 h = __float2bfloat16(f);
    return *reinterpret_cast<unsigned short*>(&h);
}

// ---------------------------------------------------------------------------
// W (k,n) fp32 -> Wt (n,k) bf16, 32x32 LDS tile transpose
// ---------------------------------------------------------------------------
__global__ __launch_bounds__(256) void transpose_wt(
    const float* __restrict__ in, __hip_bfloat16* __restrict__ out)
{
    __shared__ float s[32][33];
    const int c = threadIdx.x & 31, r8 = threadIdx.x >> 5;
    const int kt = blockIdx.x * 32, nt = blockIdx.y * 32;
#pragma unroll
    for (int rr = 0; rr < 4; ++rr) {
        int k = r8 + rr * 8;
        s[k][c] = in[(size_t)(kt + k) * HID + nt + c];
    }
    __syncthreads();
#pragma unroll
    for (int rr = 0; rr < 4; ++rr) {
        int n = r8 + rr * 8;
        out[(size_t)(nt + n) * HID + kt + c] = __float2bfloat16(s[c][n]);
    }
}

// ---------------------------------------------------------------------------
// K1 dots GEMM: bf16 MFMA 16x16x32, 128x128 tile, on-the-fly fp32->bf16 A
// staging. Epilogue: +bias, relu, *RH, reduce over 16 lanes -> dots (fp32).
// Near-threshold rows get exact fp32 recompute in fixup_kernel.
// ---------------------------------------------------------------------------
__global__ __launch_bounds__(256) void gemm_k_dots(
    const float* __restrict__ A,             // (8192, 768) fp32
    const __hip_bfloat16* __restrict__ Bt,   // (768, 768) = K1_w^T bf16
    const float* __restrict__ bias,
    const float* __restrict__ RH,            // (H*HD) flat
    float* __restrict__ dots)                // (BS*H, L) fp32
{
    __shared__ __hip_bfloat16 As[128][40];
    __shared__ __hip_bfloat16 Bs[128][40];

    const int tid = threadIdx.x;
    const int m0 = blockIdx.x * 128, n0 = blockIdx.y * 128;
    const int wid = tid >> 6, lane = tid & 63;
    const int quad = lane >> 4, lm = lane & 15;
    const int wm = wid & 1, wn = wid >> 1;

    f32x4 acc[4][4] = {};

    for (int k0 = 0; k0 < HID; k0 += 32) {
#pragma unroll
        for (int it = 0; it < 4; ++it) {
            int slot = tid + it * 256;            // 0..1023
            int r = slot & 127, kq = slot >> 7;   // kq 0..7, 4 floats
            float4 v = *(const float4*)&A[(size_t)(m0 + r) * HID + k0 + kq * 4];
            ushort4 o;
            o.x = f2bf_bits(v.x); o.y = f2bf_bits(v.y);
            o.z = f2bf_bits(v.z); o.w = f2bf_bits(v.w);
            *(ushort4*)&As[r][kq * 4] = o;
        }
#pragma unroll
        for (int it = 0; it < 2; ++it) {
            int slot = tid + it * 256;
            int r = slot & 127, kq = slot >> 7;   // kq 0..3, 8 bf16
            *(float4*)&Bs[r][kq * 8] =
                *(const float4*)&Bt[(size_t)(n0 + r) * HID + k0 + kq * 8];
        }
        __syncthreads();
        s8v af[4], bf[4];
#pragma unroll
        for (int i = 0; i < 4; ++i)
            af[i] = *(const s8v*)&As[wm * 64 + i * 16 + lm][quad * 8];
#pragma unroll
        for (int j = 0; j < 4; ++j)
            bf[j] = *(const s8v*)&Bs[wn * 64 + j * 16 + lm][quad * 8];
#pragma unroll
        for (int i = 0; i < 4; ++i)
#pragma unroll
            for (int j = 0; j < 4; ++j)
                acc[i][j] = __builtin_amdgcn_mfma_f32_16x16x32_bf16(
                    af[i], bf[j], acc[i][j], 0, 0, 0);
        __syncthreads();
    }

    // wave covers cols head*64 + j*16 + lm, head = blockIdx.y*2 + wn
    const int head = blockIdx.y * 2 + wn;
    float bj[4], rj[4];
#pragma unroll
    for (int j = 0; j < 4; ++j) {
        bj[j] = bias[head * 64 + j * 16 + lm];
        rj[j] = RH[head * 64 + j * 16 + lm];
    }
#pragma unroll
    for (int i = 0; i < 4; ++i) {
        int row0 = m0 + wm * 64 + i * 16 + quad * 4;
#pragma unroll
        for (int reg = 0; reg < 4; ++reg) {
            float p = 0.f;
#pragma unroll
            for (int j = 0; j < 4; ++j)
                p = fmaf(fmaxf(acc[i][j][reg] + bj[j], 0.f), rj[j], p);
            p += __shfl_xor(p, 1, 64);
            p += __shfl_xor(p, 2, 64);
            p += __shfl_xor(p, 4, 64);
            p += __shfl_xor(p, 8, 64);
            if (lm == 0) {
                int row = row0 + reg;
                int b = row >> 11, l = row & (L - 1);
                dots[((b * H + head) << 11) + l] = p;
            }
        }
    }
}

// ---------------------------------------------------------------------------
// Fix-up: recompute dots in exact fp32 where |dot-0.5| < MARGIN.
// Grid (BS*H, 8): each block scans 256 l's, recomputes flagged ones in
// batches of 8 (hs rows staged in LDS, W column-slice reads coalesced).
// ---------------------------------------------------------------------------
__global__ __launch_bounds__(256) void fixup_kernel(
    const float* __restrict__ hs,      // (BS*L, 768) fp32
    const float* __restrict__ W,       // (768, 768) K1_w fp32
    const float* __restrict__ bias,
    const float* __restrict__ RH,
    float* __restrict__ dots)
{
    __shared__ int list[256];
    __shared__ int cnt;
    __shared__ float hrow[8][HID];
    __shared__ float psum[4][64];

    const int bh = blockIdx.x;
    const int b = bh / H, h = bh % H;
    const int tid = threadIdx.x;

    if (tid == 0) cnt = 0;
    __syncthreads();
    {
        int l = blockIdx.y * 256 + tid;
        float dv = dots[((size_t)bh << 11) + l];
        if (fabsf(dv - 0.5f) < MARGIN) {
            int p = atomicAdd(&cnt, 1);
            list[p] = l;
        }
    }
    __syncthreads();
    const int n = cnt;

    for (int base = 0; base < n; base += 8) {
        int nb = min(8, n - base);
        for (int f = 0; f < nb; ++f) {
            int ll = list[base + f];
            for (int k = tid; k < HID; k += 256)
                hrow[f][k] = hs[((size_t)b * L + ll) * HID + k];
        }
        __syncthreads();
        const int d = tid & 63, ks = tid >> 6;
        float acc[8] = {};
        for (int k = ks; k < HID; k += 4) {
            float wv = W[(size_t)k * HID + h * 64 + d];
#pragma unroll
            for (int f = 0; f < 8; ++f)
                acc[f] = fmaf(wv, hrow[f][k], acc[f]);
        }
        for (int f = 0; f < nb; ++f) {
            psum[ks][d] = acc[f];
            __syncthreads();
            if (tid < 64) {
                float v = psum[0][tid] + psum[1][tid] + psum[2][tid] +
                          psum[3][tid] + bias[h * 64 + tid];
                v = fmaxf(v, 0.f) * RH[h * 64 + tid];
#pragma unroll
                for (int s = 1; s < 64; s <<= 1) v += __shfl_xor(v, s, 64);
                if (tid == 0) dots[((size_t)bh << 11) + list[base + f]] = v;
            }
            __syncthreads();
        }
    }
}

// ---------------------------------------------------------------------------
// V1 GEMM: bf16 MFMA 16x16x32, 128x128 tile, on-the-fly fp32->bf16 A.
// Epilogue: +bias, relu, store bf16.
// ---------------------------------------------------------------------------
__global__ __launch_bounds__(256) void gemm_v1_mfma(
    const float* __restrict__ A,             // (8192, 768) fp32
    const __hip_bfloat16* __restrict__ Bt,   // (768, 768) = V1_w^T bf16
    const float* __restrict__ bias,
    __hip_bfloat16* __restrict__ C)          // (8192, 768) relu'd
{
    __shared__ __hip_bfloat16 As[128][40];
    __shared__ __hip_bfloat16 Bs[128][40];

    const int tid = threadIdx.x;
    const int m0 = blockIdx.x * 128, n0 = blockIdx.y * 128;
    const int wid = tid >> 6, lane = tid & 63;
    const int quad = lane >> 4, lm = lane & 15;
    const int wm = wid & 1, wn = wid >> 1;

    f32x4 acc[4][4] = {};

    for (int k0 = 0; k0 < HID; k0 += 32) {
#pragma unroll
        for (int it = 0; it < 4; ++it) {
            int slot = tid + it * 256;
            int r = slot & 127, kq = slot >> 7;
            float4 v = *(const float4*)&A[(size_t)(m0 + r) * HID + k0 + kq * 4];
            ushort4 o;
            o.x = f2bf_bits(v.x); o.y = f2bf_bits(v.y);
            o.z = f2bf_bits(v.z); o.w = f2bf_bits(v.w);
            *(ushort4*)&As[r][kq * 4] = o;
        }
#pragma unroll
        for (int it = 0; it < 2; ++it) {
            int slot = tid + it * 256;
            int r = slot & 127, kq = slot >> 7;
            *(float4*)&Bs[r][kq * 8] =
                *(const float4*)&Bt[(size_t)(n0 + r) * HID + k0 + kq * 8];
        }
        __syncthreads();
        s8v af[4], bf[4];
#pragma unroll
        for (int i = 0; i < 4; ++i)
            af[i] = *(const s8v*)&As[wm * 64 + i * 16 + lm][quad * 8];
#pragma unroll
        for (int j = 0; j < 4; ++j)
            bf[j] = *(const s8v*)&Bs[wn * 64 + j * 16 + lm][quad * 8];
#pragma unroll
        for (int i = 0; i < 4; ++i)
#pragma unroll
            for (int j = 0; j < 4; ++j)
                acc[i][j] = __builtin_amdgcn_mfma_f32_16x16x32_bf16(
                    af[i], bf[j], acc[i][j], 0, 0, 0);
        __syncthreads();
    }

#pragma unroll
    for (int i = 0; i < 4; ++i) {
        int row_b = m0 + wm * 64 + i * 16 + quad * 4;
#pragma unroll
        for (int j = 0; j < 4; ++j) {
            int col = n0 + wn * 64 + j * 16 + lm;
            float bsv = bias[col];
#pragma unroll
            for (int reg = 0; reg < 4; ++reg) {
                float v = acc[i][j][reg] + bsv;
                C[(size_t)(row_b + reg) * HID + col] =
                    __float2bfloat16(fmaxf(v, 0.f));
            }
        }
    }
}

// ---------------------------------------------------------------------------
// Parallel rank/select scan over dots>0.5. One block per (b,h).
// ---------------------------------------------------------------------------
__global__ __launch_bounds__(256) void scan_kernel(
    const float* __restrict__ dots,   // (BS*H, L)
    short* __restrict__ fm,
    short* __restrict__ bm)
{
    __shared__ unsigned short P[L];
    __shared__ unsigned short S[L];
    __shared__ int wsum[4];

    const int bh = blockIdx.x;
    const int b = bh / H, h = bh % H;
    const int tid = threadIdx.x;
    const int base = tid * 8;
    const int lane = tid & 63, w = tid >> 6;

    int m[8], c[8];
    int run = 0;
#pragma unroll
    for (int i = 0; i < 8; ++i) {
        int l = base + i;
        m[i] = (l >= 1 && dots[((size_t)bh << 11) + l] > 0.5f) ? 1 : 0;
        run += m[i];
        c[i] = run;
    }
    int sc = run;
#pragma unroll
    for (int s = 1; s < 64; s <<= 1) {
        int v = __shfl_up(sc, s, 64);
        if (lane >= s) sc += v;
    }
    if (lane == 63) wsum[w] = sc;
    __syncthreads();
    int woff = 0;
    for (int i = 0; i < 4; ++i) if (i < w) woff += wsum[i];
    const int ex = woff + sc - run;

#pragma unroll
    for (int i = 0; i < 8; ++i) {
        int l = base + i;
        int pc = ex + c[i];
        P[l] = (unsigned short)pc;
        if (m[i]) S[pc] = (unsigned short)l;
    }
    __syncthreads();
    const int T = P[L - 1];

#pragma unroll
    for (int i = 0; i < 8; ++i) {
        int l = base + i;
        int cc = ex + c[i];
        union { unsigned short s[16]; uint4 q[2]; } uf, ub;
#pragma unroll
        for (int r = 0; r < 16; ++r)
            uf.s[r] = (cc - r >= 1) ? S[cc - r] : (unsigned short)0;
        int cp = (l >= 1) ? (int)P[l - 1] : 0;
#pragma unroll
        for (int r = 0; r < 16; ++r) {
            int j = cp + 1 + r;
            ub.s[r] = (l >= 1 && j <= T) ? S[j] : (unsigned short)0;
        }
        size_t off = ((size_t)(b * L + l) * H + h) * R;
        *(uint4*)&fm[off] = uf.q[0];
        *(uint4*)&fm[off + 8] = uf.q[1];
        *(uint4*)&bm[off] = ub.q[0];
        *(uint4*)&bm[off + 8] = ub.q[1];
    }
}

// ---------------------------------------------------------------------------
// Gather + weighted sum. 192 threads, TWO l-values per block.
// ---------------------------------------------------------------------------
__global__ __launch_bounds__(192) void gather_kernel(
    const __hip_bfloat16* __restrict__ V1,   // (8192, 768) bf16
    const short* __restrict__ fm,
    const short* __restrict__ bm,
    const float* __restrict__ bw,            // (H, 2R)
    float* __restrict__ out)                 // (8192, 768) fp32
{
    __shared__ short sidx[2][2][H][R];
    __shared__ float sw[2][H][R];

    const int bl0 = blockIdx.x * 2;
    const int b = bl0 >> 11;
    const int tid = threadIdx.x;

    for (int i = tid; i < 2 * 2 * H * R; i += 192) {
        int ls = i / (2 * H * R), rem = i % (2 * H * R);
        int dir = rem / (H * R), hr = rem % (H * R);
        int h = hr >> 4, r = hr & 15;
        const short* src = dir ? bm : fm;
        sidx[ls][dir][h][r] = src[((size_t)(bl0 + ls) * H + h) * R + r];
    }
    for (int i = tid; i < 2 * H * R; i += 192) {
        int dir = i / (H * R), hr = i % (H * R);
        int h = hr >> 4, r = hr & 15;
        sw[dir][h][r] = bw[h * (2 * R) + dir * R + r];
    }
    __syncthreads();

    const int ls = tid / 96, t = tid % 96;
    const int h = t >> 3, d8 = t & 7;
    const __hip_bfloat16* Vb = V1 + (size_t)b * L * HID;

    float a[8] = {};
#pragma unroll
    for (int slot = 0; slot < 32; ++slot) {
        int dir = slot >> 4, r = slot & 15;
        int idx = sidx[ls][dir][h][r];
        float wv = sw[dir][h][r];
        const __hip_bfloat16* p = Vb + (size_t)idx * HID + h * HD + d8 * 8;
        uint4 uv = *(const uint4*)p;
        a[0] = fmaf(wv, __uint_as_float(uv.x << 16), a[0]);
        a[1] = fmaf(wv, __uint_as_float(uv.x & 0xffff0000u), a[1]);
        a[2] = fmaf(wv, __uint_as_float(uv.y << 16), a[2]);
        a[3] = fmaf(wv, __uint_as_float(uv.y & 0xffff0000u), a[3]);
        a[4] = fmaf(wv, __uint_as_float(uv.z << 16), a[4]);
        a[5] = fmaf(wv, __uint_as_float(uv.z & 0xffff0000u), a[5]);
        a[6] = fmaf(wv, __uint_as_float(uv.w << 16), a[6]);
        a[7] = fmaf(wv, __uint_as_float(uv.w & 0xffff0000u), a[7]);
    }
    float* op = &out[(size_t)(bl0 + ls) * HID + h * HD + d8 * 8];
    float4 o0, o1;
    o0.x = a[0]; o0.y = a[1]; o0.z = a[2]; o0.w = a[3];
    o1.x = a[4]; o1.y = a[5]; o1.z = a[6]; o1.w = a[7];
    *(float4*)op = o0;
    *(float4*)(op + 4) = o1;
}

extern "C" void kernel_launch(void* const* d_in, const int* in_sizes, int n_in,
                              void* d_out, int out_size, void* d_ws, size_t ws_size,
                              hipStream_t stream) {
    const float* hs  = (const float*)d_in[0];
    const float* K1w = (const float*)d_in[1];
    const float* K1b = (const float*)d_in[2];
    const float* V1w = (const float*)d_in[3];
    const float* V1b = (const float*)d_in[4];
    const float* RH  = (const float*)d_in[5];
    const float* bw  = (const float*)d_in[6];
    float* out = (float*)d_out;

    // workspace layout (no aliasing; total 21,626,880 B)
    char* ws = (char*)d_ws;
    __hip_bfloat16* WtV = (__hip_bfloat16*)ws;                 // 1,179,648
    __hip_bfloat16* WtK = (__hip_bfloat16*)(ws + 1179648);     // 1,179,648
    __hip_bfloat16* V1  = (__hip_bfloat16*)(ws + 2359296);     // 12,582,912
    float* dots = (float*)(ws + 14942208);                     //   393,216
    short* fm   = (short*)(ws + 15335424);                     // 3,145,728
    short* bm   = (short*)(ws + 18481152);                     // 3,145,728

    transpose_wt<<<dim3(HID / 32, HID / 32), 256, 0, stream>>>(V1w, WtV);
    transpose_wt<<<dim3(HID / 32, HID / 32), 256, 0, stream>>>(K1w, WtK);
    gemm_k_dots<<<dim3(BS * L / 128, HID / 128), 256, 0, stream>>>(hs, WtK, K1b, RH, dots);
    fixup_kernel<<<dim3(BS * H, 8), 256, 0, stream>>>(hs, K1w, K1b, RH, dots);
    gemm_v1_mfma<<<dim3(BS * L / 128, HID / 128), 256, 0, stream>>>(hs, WtV, V1b, V1);
    scan_kernel<<<BS * H, 256, 0, stream>>>(dots, fm, bm);
    gather_kernel<<<BS * L / 2, 192, 0, stream>>>(V1, fm, bm, bw, out);
}

// Round 5
// 227.768 us; speedup vs baseline: 2.7502x; 1.2194x over previous
//
#include <hip/hip_runtime.h>
#include <hip/hip_bf16.h>

#define BS 4
#define L 2048
#define H 12
#define HD 64
#define R 16
#define HID 768
#define MARGIN 0.02f
#define FIXCAP 16384
#define FIXGRID 1024
// M = BS*L = 8192, N = 768, K = 768

typedef __attribute__((ext_vector_type(8))) short s8v;   // 8 bf16 (4 VGPRs)
typedef __attribute__((ext_vector_type(4))) float f32x4;

static __device__ __forceinline__ unsigned short f2bf_bits(float f) {
    __hip_bfloat16 h = __float2bfloat16(f);
    return *reinterpret_cast<unsigned short*>(&h);
}

// ---------------------------------------------------------------------------
__global__ void zero_cnt(int* __restrict__ cnt) { if (threadIdx.x == 0) *cnt = 0; }

// ---------------------------------------------------------------------------
// W (k,n) fp32 -> Wt (n,k) bf16, 32x32 LDS tile transpose
// ---------------------------------------------------------------------------
__global__ __launch_bounds__(256) void transpose_wt(
    const float* __restrict__ in, __hip_bfloat16* __restrict__ out)
{
    __shared__ float s[32][33];
    const int c = threadIdx.x & 31, r8 = threadIdx.x >> 5;
    const int kt = blockIdx.x * 32, nt = blockIdx.y * 32;
#pragma unroll
    for (int rr = 0; rr < 4; ++rr) {
        int k = r8 + rr * 8;
        s[k][c] = in[(size_t)(kt + k) * HID + nt + c];
    }
    __syncthreads();
#pragma unroll
    for (int rr = 0; rr < 4; ++rr) {
        int n = r8 + rr * 8;
        out[(size_t)(nt + n) * HID + kt + c] = __float2bfloat16(s[c][n]);
    }
}

// ---------------------------------------------------------------------------
// K1 dots GEMM: bf16 MFMA, 128x128 tile. Epilogue: +bias, relu, *RH,
// 16-lane reduce -> dots; near-threshold rows pushed to global fix-up list.
// ---------------------------------------------------------------------------
__global__ __launch_bounds__(256) void gemm_k_dots(
    const float* __restrict__ A,             // (8192, 768) fp32
    const __hip_bfloat16* __restrict__ Bt,   // (768, 768) = K1_w^T bf16
    const float* __restrict__ bias,
    const float* __restrict__ RH,            // (H*HD) flat
    float* __restrict__ dots,                // (BS*H, L) fp32
    int* __restrict__ fixlist,               // packed row*16+head
    int* __restrict__ fixcnt)
{
    __shared__ __hip_bfloat16 As[128][40];
    __shared__ __hip_bfloat16 Bs[128][40];

    const int tid = threadIdx.x;
    const int m0 = blockIdx.x * 128, n0 = blockIdx.y * 128;
    const int wid = tid >> 6, lane = tid & 63;
    const int quad = lane >> 4, lm = lane & 15;
    const int wm = wid & 1, wn = wid >> 1;

    f32x4 acc[4][4] = {};

    for (int k0 = 0; k0 < HID; k0 += 32) {
#pragma unroll
        for (int it = 0; it < 4; ++it) {
            int slot = tid + it * 256;
            int r = slot & 127, kq = slot >> 7;
            float4 v = *(const float4*)&A[(size_t)(m0 + r) * HID + k0 + kq * 4];
            ushort4 o;
            o.x = f2bf_bits(v.x); o.y = f2bf_bits(v.y);
            o.z = f2bf_bits(v.z); o.w = f2bf_bits(v.w);
            *(ushort4*)&As[r][kq * 4] = o;
        }
#pragma unroll
        for (int it = 0; it < 2; ++it) {
            int slot = tid + it * 256;
            int r = slot & 127, kq = slot >> 7;
            *(float4*)&Bs[r][kq * 8] =
                *(const float4*)&Bt[(size_t)(n0 + r) * HID + k0 + kq * 8];
        }
        __syncthreads();
        s8v af[4], bf[4];
#pragma unroll
        for (int i = 0; i < 4; ++i)
            af[i] = *(const s8v*)&As[wm * 64 + i * 16 + lm][quad * 8];
#pragma unroll
        for (int j = 0; j < 4; ++j)
            bf[j] = *(const s8v*)&Bs[wn * 64 + j * 16 + lm][quad * 8];
#pragma unroll
        for (int i = 0; i < 4; ++i)
#pragma unroll
            for (int j = 0; j < 4; ++j)
                acc[i][j] = __builtin_amdgcn_mfma_f32_16x16x32_bf16(
                    af[i], bf[j], acc[i][j], 0, 0, 0);
        __syncthreads();
    }

    const int head = blockIdx.y * 2 + wn;
    float bj[4], rj[4];
#pragma unroll
    for (int j = 0; j < 4; ++j) {
        bj[j] = bias[head * 64 + j * 16 + lm];
        rj[j] = RH[head * 64 + j * 16 + lm];
    }
#pragma unroll
    for (int i = 0; i < 4; ++i) {
        int row0 = m0 + wm * 64 + i * 16 + quad * 4;
#pragma unroll
        for (int reg = 0; reg < 4; ++reg) {
            float p = 0.f;
#pragma unroll
            for (int j = 0; j < 4; ++j)
                p = fmaf(fmaxf(acc[i][j][reg] + bj[j], 0.f), rj[j], p);
            p += __shfl_xor(p, 1, 64);
            p += __shfl_xor(p, 2, 64);
            p += __shfl_xor(p, 4, 64);
            p += __shfl_xor(p, 8, 64);
            if (lm == 0) {
                int row = row0 + reg;
                int b = row >> 11, l = row & (L - 1);
                dots[((b * H + head) << 11) + l] = p;
                if (fabsf(p - 0.5f) < MARGIN) {
                    int idx = atomicAdd(fixcnt, 1);
                    if (idx < FIXCAP) fixlist[idx] = row * 16 + head;
                }
            }
        }
    }
}

// ---------------------------------------------------------------------------
// Fix-up v2: one block per flagged row (grid-stride over compacted list).
// Exact fp32 recompute: hs row staged in LDS, W reads coalesced over d,
// k-loop unrolled 8-deep for load pipelining.
// ---------------------------------------------------------------------------
__global__ __launch_bounds__(256) void fixup_kernel(
    const float* __restrict__ hs,      // (BS*L, 768) fp32
    const float* __restrict__ W,       // (768, 768) K1_w fp32
    const float* __restrict__ bias,
    const float* __restrict__ RH,
    const int* __restrict__ fixlist,
    const int* __restrict__ fixcnt,
    float* __restrict__ dots)
{
    __shared__ float hrow[HID];
    __shared__ float psum[4][64];

    const int tid = threadIdx.x;
    const int n = min(*fixcnt, FIXCAP);

    for (int item = blockIdx.x; item < n; item += FIXGRID) {
        int packed = fixlist[item];
        int row = packed >> 4, head = packed & 15;
        int b = row >> 11, l = row & (L - 1);

#pragma unroll
        for (int i = 0; i < 3; ++i)
            hrow[tid + i * 256] = hs[(size_t)row * HID + tid + i * 256];
        __syncthreads();

        const int d = tid & 63, kq = tid >> 6;
        float a0 = 0.f, a1 = 0.f;
#pragma unroll 8
        for (int i = 0; i < 96; ++i) {
            int k = kq + i * 8;
            a0 = fmaf(W[(size_t)k * HID + head * 64 + d], hrow[k], a0);
            a1 = fmaf(W[(size_t)(k + 4) * HID + head * 64 + d], hrow[k + 4], a1);
        }
        psum[kq][d] = a0 + a1;
        __syncthreads();
        if (tid < 64) {
            float v = psum[0][tid] + psum[1][tid] + psum[2][tid] +
                      psum[3][tid] + bias[head * 64 + tid];
            v = fmaxf(v, 0.f) * RH[head * 64 + tid];
#pragma unroll
            for (int s = 1; s < 64; s <<= 1) v += __shfl_xor(v, s, 64);
            if (tid == 0) dots[((size_t)(b * H + head) << 11) + l] = v;
        }
        __syncthreads();
    }
}

// ---------------------------------------------------------------------------
// V1 GEMM: bf16 MFMA 16x16x32, 128x128 tile, on-the-fly fp32->bf16 A.
// ---------------------------------------------------------------------------
__global__ __launch_bounds__(256) void gemm_v1_mfma(
    const float* __restrict__ A,             // (8192, 768) fp32
    const __hip_bfloat16* __restrict__ Bt,   // (768, 768) = V1_w^T bf16
    const float* __restrict__ bias,
    __hip_bfloat16* __restrict__ C)          // (8192, 768) relu'd
{
    __shared__ __hip_bfloat16 As[128][40];
    __shared__ __hip_bfloat16 Bs[128][40];

    const int tid = threadIdx.x;
    const int m0 = blockIdx.x * 128, n0 = blockIdx.y * 128;
    const int wid = tid >> 6, lane = tid & 63;
    const int quad = lane >> 4, lm = lane & 15;
    const int wm = wid & 1, wn = wid >> 1;

    f32x4 acc[4][4] = {};

    for (int k0 = 0; k0 < HID; k0 += 32) {
#pragma unroll
        for (int it = 0; it < 4; ++it) {
            int slot = tid + it * 256;
            int r = slot & 127, kq = slot >> 7;
            float4 v = *(const float4*)&A[(size_t)(m0 + r) * HID + k0 + kq * 4];
            ushort4 o;
            o.x = f2bf_bits(v.x); o.y = f2bf_bits(v.y);
            o.z = f2bf_bits(v.z); o.w = f2bf_bits(v.w);
            *(ushort4*)&As[r][kq * 4] = o;
        }
#pragma unroll
        for (int it = 0; it < 2; ++it) {
            int slot = tid + it * 256;
            int r = slot & 127, kq = slot >> 7;
            *(float4*)&Bs[r][kq * 8] =
                *(const float4*)&Bt[(size_t)(n0 + r) * HID + k0 + kq * 8];
        }
        __syncthreads();
        s8v af[4], bf[4];
#pragma unroll
        for (int i = 0; i < 4; ++i)
            af[i] = *(const s8v*)&As[wm * 64 + i * 16 + lm][quad * 8];
#pragma unroll
        for (int j = 0; j < 4; ++j)
            bf[j] = *(const s8v*)&Bs[wn * 64 + j * 16 + lm][quad * 8];
#pragma unroll
        for (int i = 0; i < 4; ++i)
#pragma unroll
            for (int j = 0; j < 4; ++j)
                acc[i][j] = __builtin_amdgcn_mfma_f32_16x16x32_bf16(
                    af[i], bf[j], acc[i][j], 0, 0, 0);
        __syncthreads();
    }

#pragma unroll
    for (int i = 0; i < 4; ++i) {
        int row_b = m0 + wm * 64 + i * 16 + quad * 4;
#pragma unroll
        for (int j = 0; j < 4; ++j) {
            int col = n0 + wn * 64 + j * 16 + lm;
            float bsv = bias[col];
#pragma unroll
            for (int reg = 0; reg < 4; ++reg) {
                float v = acc[i][j][reg] + bsv;
                C[(size_t)(row_b + reg) * HID + col] =
                    __float2bfloat16(fmaxf(v, 0.f));
            }
        }
    }
}

// ---------------------------------------------------------------------------
// Parallel rank/select scan over dots>0.5. One block per (b,h).
// ---------------------------------------------------------------------------
__global__ __launch_bounds__(256) void scan_kernel(
    const float* __restrict__ dots,   // (BS*H, L)
    short* __restrict__ fm,
    short* __restrict__ bm)
{
    __shared__ unsigned short P[L];
    __shared__ unsigned short S[L];
    __shared__ int wsum[4];

    const int bh = blockIdx.x;
    const int b = bh / H, h = bh % H;
    const int tid = threadIdx.x;
    const int base = tid * 8;
    const int lane = tid & 63, w = tid >> 6;

    int m[8], c[8];
    int run = 0;
#pragma unroll
    for (int i = 0; i < 8; ++i) {
        int l = base + i;
        m[i] = (l >= 1 && dots[((size_t)bh << 11) + l] > 0.5f) ? 1 : 0;
        run += m[i];
        c[i] = run;
    }
    int sc = run;
#pragma unroll
    for (int s = 1; s < 64; s <<= 1) {
        int v = __shfl_up(sc, s, 64);
        if (lane >= s) sc += v;
    }
    if (lane == 63) wsum[w] = sc;
    __syncthreads();
    int woff = 0;
    for (int i = 0; i < 4; ++i) if (i < w) woff += wsum[i];
    const int ex = woff + sc - run;

#pragma unroll
    for (int i = 0; i < 8; ++i) {
        int l = base + i;
        int pc = ex + c[i];
        P[l] = (unsigned short)pc;
        if (m[i]) S[pc] = (unsigned short)l;
    }
    __syncthreads();
    const int T = P[L - 1];

#pragma unroll
    for (int i = 0; i < 8; ++i) {
        int l = base + i;
        int cc = ex + c[i];
        union { unsigned short s[16]; uint4 q[2]; } uf, ub;
#pragma unroll
        for (int r = 0; r < 16; ++r)
            uf.s[r] = (cc - r >= 1) ? S[cc - r] : (unsigned short)0;
        int cp = (l >= 1) ? (int)P[l - 1] : 0;
#pragma unroll
        for (int r = 0; r < 16; ++r) {
            int j = cp + 1 + r;
            ub.s[r] = (l >= 1 && j <= T) ? S[j] : (unsigned short)0;
        }
        size_t off = ((size_t)(b * L + l) * H + h) * R;
        *(uint4*)&fm[off] = uf.q[0];
        *(uint4*)&fm[off + 8] = uf.q[1];
        *(uint4*)&bm[off] = ub.q[0];
        *(uint4*)&bm[off + 8] = ub.q[1];
    }
}

// ---------------------------------------------------------------------------
// Gather + weighted sum. 192 threads, TWO l-values per block.
// ---------------------------------------------------------------------------
__global__ __launch_bounds__(192) void gather_kernel(
    const __hip_bfloat16* __restrict__ V1,   // (8192, 768) bf16
    const short* __restrict__ fm,
    const short* __restrict__ bm,
    const float* __restrict__ bw,            // (H, 2R)
    float* __restrict__ out)                 // (8192, 768) fp32
{
    __shared__ short sidx[2][2][H][R];
    __shared__ float sw[2][H][R];

    const int bl0 = blockIdx.x * 2;
    const int b = bl0 >> 11;
    const int tid = threadIdx.x;

    for (int i = tid; i < 2 * 2 * H * R; i += 192) {
        int ls = i / (2 * H * R), rem = i % (2 * H * R);
        int dir = rem / (H * R), hr = rem % (H * R);
        int h = hr >> 4, r = hr & 15;
        const short* src = dir ? bm : fm;
        sidx[ls][dir][h][r] = src[((size_t)(bl0 + ls) * H + h) * R + r];
    }
    for (int i = tid; i < 2 * H * R; i += 192) {
        int dir = i / (H * R), hr = i % (H * R);
        int h = hr >> 4, r = hr & 15;
        sw[dir][h][r] = bw[h * (2 * R) + dir * R + r];
    }
    __syncthreads();

    const int ls = tid / 96, t = tid % 96;
    const int h = t >> 3, d8 = t & 7;
    const __hip_bfloat16* Vb = V1 + (size_t)b * L * HID;

    float a[8] = {};
#pragma unroll
    for (int slot = 0; slot < 32; ++slot) {
        int dir = slot >> 4, r = slot & 15;
        int idx = sidx[ls][dir][h][r];
        float wv = sw[dir][h][r];
        const __hip_bfloat16* p = Vb + (size_t)idx * HID + h * HD + d8 * 8;
        uint4 uv = *(const uint4*)p;
        a[0] = fmaf(wv, __uint_as_float(uv.x << 16), a[0]);
        a[1] = fmaf(wv, __uint_as_float(uv.x & 0xffff0000u), a[1]);
        a[2] = fmaf(wv, __uint_as_float(uv.y << 16), a[2]);
        a[3] = fmaf(wv, __uint_as_float(uv.y & 0xffff0000u), a[3]);
        a[4] = fmaf(wv, __uint_as_float(uv.z << 16), a[4]);
        a[5] = fmaf(wv, __uint_as_float(uv.z & 0xffff0000u), a[5]);
        a[6] = fmaf(wv, __uint_as_float(uv.w << 16), a[6]);
        a[7] = fmaf(wv, __uint_as_float(uv.w & 0xffff0000u), a[7]);
    }
    float* op = &out[(size_t)(bl0 + ls) * HID + h * HD + d8 * 8];
    float4 o0, o1;
    o0.x = a[0]; o0.y = a[1]; o0.z = a[2]; o0.w = a[3];
    o1.x = a[4]; o1.y = a[5]; o1.z = a[6]; o1.w = a[7];
    *(float4*)op = o0;
    *(float4*)(op + 4) = o1;
}

extern "C" void kernel_launch(void* const* d_in, const int* in_sizes, int n_in,
                              void* d_out, int out_size, void* d_ws, size_t ws_size,
                              hipStream_t stream) {
    const float* hs  = (const float*)d_in[0];
    const float* K1w = (const float*)d_in[1];
    const float* K1b = (const float*)d_in[2];
    const float* V1w = (const float*)d_in[3];
    const float* V1b = (const float*)d_in[4];
    const float* RH  = (const float*)d_in[5];
    const float* bw  = (const float*)d_in[6];
    float* out = (float*)d_out;

    // workspace layout (total ~21.7 MB)
    char* ws = (char*)d_ws;
    __hip_bfloat16* WtV = (__hip_bfloat16*)ws;                 // 1,179,648
    __hip_bfloat16* WtK = (__hip_bfloat16*)(ws + 1179648);     // 1,179,648
    __hip_bfloat16* V1  = (__hip_bfloat16*)(ws + 2359296);     // 12,582,912
    float* dots = (float*)(ws + 14942208);                     //   393,216
    short* fm   = (short*)(ws + 15335424);                     // 3,145,728
    short* bm   = (short*)(ws + 18481152);                     // 3,145,728
    int* fixlist = (int*)(ws + 21626880);                      //    65,536
    int* fixcnt  = (int*)(ws + 21692416);                      //         4

    transpose_wt<<<dim3(HID / 32, HID / 32), 256, 0, stream>>>(V1w, WtV);
    transpose_wt<<<dim3(HID / 32, HID / 32), 256, 0, stream>>>(K1w, WtK);
    zero_cnt<<<1, 64, 0, stream>>>(fixcnt);
    gemm_k_dots<<<dim3(BS * L / 128, HID / 128), 256, 0, stream>>>(
        hs, WtK, K1b, RH, dots, fixlist, fixcnt);
    gemm_v1_mfma<<<dim3(BS * L / 128, HID / 128), 256, 0, stream>>>(hs, WtV, V1b, V1);
    fixup_kernel<<<FIXGRID, 256, 0, stream>>>(hs, K1w, K1b, RH, fixlist, fixcnt, dots);
    scan_kernel<<<BS * H, 256, 0, stream>>>(dots, fm, bm);
    gather_kernel<<<BS * L / 2, 192, 0, stream>>>(V1, fm, bm, bw, out);
}

// Round 6
// 182.009 us; speedup vs baseline: 3.4416x; 1.2514x over previous
//
#include <hip/hip_runtime.h>
#include <hip/hip_bf16.h>

#define BS 4
#define L 2048
#define H 12
#define HD 64
#define R 16
#define HID 768
#define MARGIN 0.02f
#define FIXCAP 16384
#define FIXGRID 1024
// M = BS*L = 8192, N = 768, K = 768

typedef __attribute__((ext_vector_type(8))) short s8v;   // 8 bf16 (4 VGPRs)
typedef __attribute__((ext_vector_type(4))) float f32x4;

static __device__ __forceinline__ unsigned short f2bf_bits(float f) {
    __hip_bfloat16 h = __float2bfloat16(f);
    return *reinterpret_cast<unsigned short*>(&h);
}

// ---------------------------------------------------------------------------
__global__ void zero_cnt(int* __restrict__ cnt) { if (threadIdx.x == 0) *cnt = 0; }

// ---------------------------------------------------------------------------
// W (k,n) fp32 -> Wt (n,k) bf16, 32x32 LDS tile transpose
// ---------------------------------------------------------------------------
__global__ __launch_bounds__(256) void transpose_wt(
    const float* __restrict__ in, __hip_bfloat16* __restrict__ out)
{
    __shared__ float s[32][33];
    const int c = threadIdx.x & 31, r8 = threadIdx.x >> 5;
    const int kt = blockIdx.x * 32, nt = blockIdx.y * 32;
#pragma unroll
    for (int rr = 0; rr < 4; ++rr) {
        int k = r8 + rr * 8;
        s[k][c] = in[(size_t)(kt + k) * HID + nt + c];
    }
    __syncthreads();
#pragma unroll
    for (int rr = 0; rr < 4; ++rr) {
        int n = r8 + rr * 8;
        out[(size_t)(nt + n) * HID + kt + c] = __float2bfloat16(s[c][n]);
    }
}

// ---------------------------------------------------------------------------
// Fused dual GEMM: bf16 MFMA 16x16x32, 128x128 tile, 4 waves of 64x64.
// blockIdx.y < 6  -> V1 tile (n0 = y*128):   +bias, relu, store bf16.
// blockIdx.y >= 6 -> K-dots tile (y-6)*128:  +bias, relu, *RH, 16-lane
//                    reduce -> dots, near-threshold rows -> fixlist.
// 768 blocks total (vs 2x384 serial) -> 3 blocks/CU resident.
// ---------------------------------------------------------------------------
__global__ __launch_bounds__(256) void gemm_fused(
    const float* __restrict__ A,             // (8192, 768) fp32
    const __hip_bfloat16* __restrict__ WtK,  // (768, 768) = K1_w^T bf16
    const __hip_bfloat16* __restrict__ WtV,  // (768, 768) = V1_w^T bf16
    const float* __restrict__ K1b,
    const float* __restrict__ V1b,
    const float* __restrict__ RH,            // (H*HD) flat
    float* __restrict__ dots,                // (BS*H, L) fp32
    int* __restrict__ fixlist,               // packed row*16+head
    int* __restrict__ fixcnt,
    __hip_bfloat16* __restrict__ C)          // (8192, 768) relu'd V1
{
    __shared__ __hip_bfloat16 As[128][40];
    __shared__ __hip_bfloat16 Bs[128][40];

    const int tid = threadIdx.x;
    const bool isV = blockIdx.y < 6;
    const int m0 = blockIdx.x * 128;
    const int n0 = (isV ? blockIdx.y : blockIdx.y - 6) * 128;
    const __hip_bfloat16* Bt = isV ? WtV : WtK;

    const int wid = tid >> 6, lane = tid & 63;
    const int quad = lane >> 4, lm = lane & 15;
    const int wm = wid & 1, wn = wid >> 1;

    f32x4 acc[4][4] = {};

    for (int k0 = 0; k0 < HID; k0 += 32) {
        // A stage: swizzled slot->(r,kq): consecutive lanes walk kq within a
        // row (8B writes, <=4 writers/bank = volume floor).
#pragma unroll
        for (int it = 0; it < 4; ++it) {
            int slot = tid + it * 256;            // 0..1023
            int kq = slot & 7, r = slot >> 3;     // r 0..127
            float4 v = *(const float4*)&A[(size_t)(m0 + r) * HID + k0 + kq * 4];
            ushort4 o;
            o.x = f2bf_bits(v.x); o.y = f2bf_bits(v.y);
            o.z = f2bf_bits(v.z); o.w = f2bf_bits(v.w);
            *(ushort4*)&As[r][kq * 4] = o;
        }
#pragma unroll
        for (int it = 0; it < 2; ++it) {
            int slot = tid + it * 256;            // 0..511
            int kq2 = slot & 3, r = slot >> 2;    // r 0..127, 16B chunks
            *(float4*)&Bs[r][kq2 * 8] =
                *(const float4*)&Bt[(size_t)(n0 + r) * HID + k0 + kq2 * 8];
        }
        __syncthreads();
        s8v af[4], bf[4];
#pragma unroll
        for (int i = 0; i < 4; ++i)
            af[i] = *(const s8v*)&As[wm * 64 + i * 16 + lm][quad * 8];
#pragma unroll
        for (int j = 0; j < 4; ++j)
            bf[j] = *(const s8v*)&Bs[wn * 64 + j * 16 + lm][quad * 8];
#pragma unroll
        for (int i = 0; i < 4; ++i)
#pragma unroll
            for (int j = 0; j < 4; ++j)
                acc[i][j] = __builtin_amdgcn_mfma_f32_16x16x32_bf16(
                    af[i], bf[j], acc[i][j], 0, 0, 0);
        __syncthreads();
    }

    if (isV) {
        // C/D layout: col = lane&15, row = quad*4 + reg  [m89/m91 verified]
#pragma unroll
        for (int i = 0; i < 4; ++i) {
            int row_b = m0 + wm * 64 + i * 16 + quad * 4;
#pragma unroll
            for (int j = 0; j < 4; ++j) {
                int col = n0 + wn * 64 + j * 16 + lm;
                float bsv = V1b[col];
#pragma unroll
                for (int reg = 0; reg < 4; ++reg) {
                    float v = acc[i][j][reg] + bsv;
                    C[(size_t)(row_b + reg) * HID + col] =
                        __float2bfloat16(fmaxf(v, 0.f));
                }
            }
        }
    } else {
        const int head = (n0 >> 6) + wn;      // wave covers one head's 64 cols
        float bj[4], rj[4];
#pragma unroll
        for (int j = 0; j < 4; ++j) {
            bj[j] = K1b[head * 64 + j * 16 + lm];
            rj[j] = RH[head * 64 + j * 16 + lm];
        }
#pragma unroll
        for (int i = 0; i < 4; ++i) {
            int row0 = m0 + wm * 64 + i * 16 + quad * 4;
#pragma unroll
            for (int reg = 0; reg < 4; ++reg) {
                float p = 0.f;
#pragma unroll
                for (int j = 0; j < 4; ++j)
                    p = fmaf(fmaxf(acc[i][j][reg] + bj[j], 0.f), rj[j], p);
                p += __shfl_xor(p, 1, 64);
                p += __shfl_xor(p, 2, 64);
                p += __shfl_xor(p, 4, 64);
                p += __shfl_xor(p, 8, 64);
                if (lm == 0) {
                    int row = row0 + reg;
                    int b = row >> 11, l = row & (L - 1);
                    dots[((b * H + head) << 11) + l] = p;
                    if (fabsf(p - 0.5f) < MARGIN) {
                        int idx = atomicAdd(fixcnt, 1);
                        if (idx < FIXCAP) fixlist[idx] = row * 16 + head;
                    }
                }
            }
        }
    }
}

// ---------------------------------------------------------------------------
// Fix-up: one block per flagged row (grid-stride over compacted list).
// Exact fp32 recompute: hs row staged in LDS, W reads coalesced over d.
// ---------------------------------------------------------------------------
__global__ __launch_bounds__(256) void fixup_kernel(
    const float* __restrict__ hs,      // (BS*L, 768) fp32
    const float* __restrict__ W,       // (768, 768) K1_w fp32
    const float* __restrict__ bias,
    const float* __restrict__ RH,
    const int* __restrict__ fixlist,
    const int* __restrict__ fixcnt,
    float* __restrict__ dots)
{
    __shared__ float hrow[HID];
    __shared__ float psum[4][64];

    const int tid = threadIdx.x;
    const int n = min(*fixcnt, FIXCAP);

    for (int item = blockIdx.x; item < n; item += FIXGRID) {
        int packed = fixlist[item];
        int row = packed >> 4, head = packed & 15;
        int b = row >> 11, l = row & (L - 1);

#pragma unroll
        for (int i = 0; i < 3; ++i)
            hrow[tid + i * 256] = hs[(size_t)row * HID + tid + i * 256];
        __syncthreads();

        const int d = tid & 63, kq = tid >> 6;
        float a0 = 0.f, a1 = 0.f;
#pragma unroll 8
        for (int i = 0; i < 96; ++i) {
            int k = kq + i * 8;
            a0 = fmaf(W[(size_t)k * HID + head * 64 + d], hrow[k], a0);
            a1 = fmaf(W[(size_t)(k + 4) * HID + head * 64 + d], hrow[k + 4], a1);
        }
        psum[kq][d] = a0 + a1;
        __syncthreads();
        if (tid < 64) {
            float v = psum[0][tid] + psum[1][tid] + psum[2][tid] +
                      psum[3][tid] + bias[head * 64 + tid];
            v = fmaxf(v, 0.f) * RH[head * 64 + tid];
#pragma unroll
            for (int s = 1; s < 64; s <<= 1) v += __shfl_xor(v, s, 64);
            if (tid == 0) dots[((size_t)(b * H + head) << 11) + l] = v;
        }
        __syncthreads();
    }
}

// ---------------------------------------------------------------------------
// Parallel rank/select scan over dots>0.5. One block per (b,h).
// ---------------------------------------------------------------------------
__global__ __launch_bounds__(256) void scan_kernel(
    const float* __restrict__ dots,   // (BS*H, L)
    short* __restrict__ fm,
    short* __restrict__ bm)
{
    __shared__ unsigned short P[L];
    __shared__ unsigned short S[L];
    __shared__ int wsum[4];

    const int bh = blockIdx.x;
    const int b = bh / H, h = bh % H;
    const int tid = threadIdx.x;
    const int base = tid * 8;
    const int lane = tid & 63, w = tid >> 6;

    int m[8], c[8];
    int run = 0;
#pragma unroll
    for (int i = 0; i < 8; ++i) {
        int l = base + i;
        m[i] = (l >= 1 && dots[((size_t)bh << 11) + l] > 0.5f) ? 1 : 0;
        run += m[i];
        c[i] = run;
    }
    int sc = run;
#pragma unroll
    for (int s = 1; s < 64; s <<= 1) {
        int v = __shfl_up(sc, s, 64);
        if (lane >= s) sc += v;
    }
    if (lane == 63) wsum[w] = sc;
    __syncthreads();
    int woff = 0;
    for (int i = 0; i < 4; ++i) if (i < w) woff += wsum[i];
    const int ex = woff + sc - run;

#pragma unroll
    for (int i = 0; i < 8; ++i) {
        int l = base + i;
        int pc = ex + c[i];
        P[l] = (unsigned short)pc;
        if (m[i]) S[pc] = (unsigned short)l;
    }
    __syncthreads();
    const int T = P[L - 1];

#pragma unroll
    for (int i = 0; i < 8; ++i) {
        int l = base + i;
        int cc = ex + c[i];
        union { unsigned short s[16]; uint4 q[2]; } uf, ub;
#pragma unroll
        for (int r = 0; r < 16; ++r)
            uf.s[r] = (cc - r >= 1) ? S[cc - r] : (unsigned short)0;
        int cp = (l >= 1) ? (int)P[l - 1] : 0;
#pragma unroll
        for (int r = 0; r < 16; ++r) {
            int j = cp + 1 + r;
            ub.s[r] = (l >= 1 && j <= T) ? S[j] : (unsigned short)0;
        }
        size_t off = ((size_t)(b * L + l) * H + h) * R;
        *(uint4*)&fm[off] = uf.q[0];
        *(uint4*)&fm[off + 8] = uf.q[1];
        *(uint4*)&bm[off] = ub.q[0];
        *(uint4*)&bm[off + 8] = ub.q[1];
    }
}

// ---------------------------------------------------------------------------
// Gather + weighted sum. 192 threads, TWO l-values per block.
// ---------------------------------------------------------------------------
__global__ __launch_bounds__(192) void gather_kernel(
    const __hip_bfloat16* __restrict__ V1,   // (8192, 768) bf16
    const short* __restrict__ fm,
    const short* __restrict__ bm,
    const float* __restrict__ bw,            // (H, 2R)
    float* __restrict__ out)                 // (8192, 768) fp32
{
    __shared__ short sidx[2][2][H][R];
    __shared__ float sw[2][H][R];

    const int bl0 = blockIdx.x * 2;
    const int b = bl0 >> 11;
    const int tid = threadIdx.x;

    for (int i = tid; i < 2 * 2 * H * R; i += 192) {
        int ls = i / (2 * H * R), rem = i % (2 * H * R);
        int dir = rem / (H * R), hr = rem % (H * R);
        int h = hr >> 4, r = hr & 15;
        const short* src = dir ? bm : fm;
        sidx[ls][dir][h][r] = src[((size_t)(bl0 + ls) * H + h) * R + r];
    }
    for (int i = tid; i < 2 * H * R; i += 192) {
        int dir = i / (H * R), hr = i % (H * R);
        int h = hr >> 4, r = hr & 15;
        sw[dir][h][r] = bw[h * (2 * R) + dir * R + r];
    }
    __syncthreads();

    const int ls = tid / 96, t = tid % 96;
    const int h = t >> 3, d8 = t & 7;
    const __hip_bfloat16* Vb = V1 + (size_t)b * L * HID;

    float a[8] = {};
#pragma unroll
    for (int slot = 0; slot < 32; ++slot) {
        int dir = slot >> 4, r = slot & 15;
        int idx = sidx[ls][dir][h][r];
        float wv = sw[dir][h][r];
        const __hip_bfloat16* p = Vb + (size_t)idx * HID + h * HD + d8 * 8;
        uint4 uv = *(const uint4*)p;
        a[0] = fmaf(wv, __uint_as_float(uv.x << 16), a[0]);
        a[1] = fmaf(wv, __uint_as_float(uv.x & 0xffff0000u), a[1]);
        a[2] = fmaf(wv, __uint_as_float(uv.y << 16), a[2]);
        a[3] = fmaf(wv, __uint_as_float(uv.y & 0xffff0000u), a[3]);
        a[4] = fmaf(wv, __uint_as_float(uv.z << 16), a[4]);
        a[5] = fmaf(wv, __uint_as_float(uv.z & 0xffff0000u), a[5]);
        a[6] = fmaf(wv, __uint_as_float(uv.w << 16), a[6]);
        a[7] = fmaf(wv, __uint_as_float(uv.w & 0xffff0000u), a[7]);
    }
    float* op = &out[(size_t)(bl0 + ls) * HID + h * HD + d8 * 8];
    float4 o0, o1;
    o0.x = a[0]; o0.y = a[1]; o0.z = a[2]; o0.w = a[3];
    o1.x = a[4]; o1.y = a[5]; o1.z = a[6]; o1.w = a[7];
    *(float4*)op = o0;
    *(float4*)(op + 4) = o1;
}

extern "C" void kernel_launch(void* const* d_in, const int* in_sizes, int n_in,
                              void* d_out, int out_size, void* d_ws, size_t ws_size,
                              hipStream_t stream) {
    const float* hs  = (const float*)d_in[0];
    const float* K1w = (const float*)d_in[1];
    const float* K1b = (const float*)d_in[2];
    const float* V1w = (const float*)d_in[3];
    const float* V1b = (const float*)d_in[4];
    const float* RH  = (const float*)d_in[5];
    const float* bw  = (const float*)d_in[6];
    float* out = (float*)d_out;

    // workspace layout (total ~21.7 MB)
    char* ws = (char*)d_ws;
    __hip_bfloat16* WtV = (__hip_bfloat16*)ws;                 // 1,179,648
    __hip_bfloat16* WtK = (__hip_bfloat16*)(ws + 1179648);     // 1,179,648
    __hip_bfloat16* V1  = (__hip_bfloat16*)(ws + 2359296);     // 12,582,912
    float* dots = (float*)(ws + 14942208);                     //   393,216
    short* fm   = (short*)(ws + 15335424);                     // 3,145,728
    short* bm   = (short*)(ws + 18481152);                     // 3,145,728
    int* fixlist = (int*)(ws + 21626880);                      //    65,536
    int* fixcnt  = (int*)(ws + 21692416);                      //         4

    transpose_wt<<<dim3(HID / 32, HID / 32), 256, 0, stream>>>(V1w, WtV);
    transpose_wt<<<dim3(HID / 32, HID / 32), 256, 0, stream>>>(K1w, WtK);
    zero_cnt<<<1, 64, 0, stream>>>(fixcnt);
    gemm_fused<<<dim3(BS * L / 128, 12), 256, 0, stream>>>(
        hs, WtK, WtV, K1b, V1b, RH, dots, fixlist, fixcnt, V1);
    fixup_kernel<<<FIXGRID, 256, 0, stream>>>(hs, K1w, K1b, RH, fixlist, fixcnt, dots);
    scan_kernel<<<BS * H, 256, 0, stream>>>(dots, fm, bm);
    gather_kernel<<<BS * L / 2, 192, 0, stream>>>(V1, fm, bm, bw, out);
}